// Round 1
// baseline (1152.746 us; speedup 1.0000x reference)
//
#include <hip/hip_runtime.h>

// Problem constants (from reference): out[4096,128] = A[4096,49998] @ W[0:49998,128]
#define M_ROWS 4096
#define K_EFF  49998
#define K_PAD  50048        // 782 * 64, zero-padded in Bt
#define N_EMB  128
#define BM     64
#define BK     64
#define S_SPLIT 16
#define IT_TOTAL 782        // ceil(K_EFF / BK)
#define OUT_ELEMS (M_ROWS * N_EMB)

typedef __attribute__((ext_vector_type(8))) short        short8;   // 8 bf16 = 4 VGPRs (MFMA A/B frag)
typedef __attribute__((ext_vector_type(4))) float        floatx4;  // MFMA C/D frag
typedef __attribute__((ext_vector_type(2))) float        floatx2;
typedef __attribute__((ext_vector_type(4))) unsigned int uintx4;

__device__ __forceinline__ unsigned short f2bf(float f){
  // round-to-nearest-even fp32 -> bf16 (finite inputs)
  unsigned int u = __builtin_bit_cast(unsigned int, f);
  u += 0x7fffu + ((u >> 16) & 1u);
  return (unsigned short)(u >> 16);
}

// ---------------------------------------------------------------------------
// prep: build Bt [128][K_PAD] bf16 (k-contiguous per embed dim) from
// W [50000][128] fp32 (only first 49998 rows used), and zero d_out.
// One block handles a 64(k) x 128(n) tile; LDS transpose keeps both the
// global read and the global write coalesced.
// ---------------------------------------------------------------------------
__global__ void prep_bt(const float* __restrict__ W,
                        unsigned short* __restrict__ Bt,
                        float* __restrict__ out){
  __shared__ unsigned short T[64 * 132];   // [k_local][n], +4 pad breaks bank alias
  const int tid = threadIdx.x;

  // zero the (0xAA-poisoned) output; 782*256 = 200192 threads >= 131072 float4
  const int gid = blockIdx.x * 256 + tid;
  if (gid < OUT_ELEMS / 4) ((floatx4*)out)[gid] = (floatx4)0.0f;

  const int kp0 = blockIdx.x * 64;

  // read phase: coalesced float4 rows of W, convert, store [k][n] to LDS
#pragma unroll
  for (int p = 0; p < 8; ++p){
    const int id = p * 256 + tid;
    const int r  = id >> 5;        // k_local 0..63
    const int c4 = id & 31;        // float4 index within a 128-col row
    const int kp = kp0 + r;
    floatx4 f = (floatx4)0.0f;
    if (kp < K_EFF) f = *(const floatx4*)(W + (size_t)kp * N_EMB + c4 * 4);
    const unsigned int u0 = f2bf(f.x) | ((unsigned)f2bf(f.y) << 16);
    const unsigned int u1 = f2bf(f.z) | ((unsigned)f2bf(f.w) << 16);
    *(unsigned int*)(&T[r * 132 + c4 * 4])     = u0;
    *(unsigned int*)(&T[r * 132 + c4 * 4 + 2]) = u1;
  }
  __syncthreads();

  // write phase: gather 8 k's per n, store 16B chunks, coalesced over Bt rows
#pragma unroll
  for (int p = 0; p < 4; ++p){
    const int id = p * 256 + tid;
    const int n  = id >> 3;        // 0..127
    const int c  = id & 7;         // k-chunk of 8
    unsigned short v[8];
#pragma unroll
    for (int j = 0; j < 8; ++j) v[j] = T[(c * 8 + j) * 132 + n];
    uintx4 pk;
    pk.x = v[0] | ((unsigned)v[1] << 16);
    pk.y = v[2] | ((unsigned)v[3] << 16);
    pk.z = v[4] | ((unsigned)v[5] << 16);
    pk.w = v[6] | ((unsigned)v[7] << 16);
    *(uintx4*)(Bt + (size_t)n * K_PAD + kp0 + c * 8) = pk;
  }
}

// ---------------------------------------------------------------------------
// Split-K bf16 MFMA GEMM. Block = 256 threads (4 waves). Block tile:
// 64(M) x 128(N) x 64(K-step). Wave w owns rows 16w..16w+15, all 128 cols
// (8 accumulator tiles of 16x16). Grid = 64 M-tiles x 16 K-chunks.
// fp32 atomicAdd epilogue into the pre-zeroed output.
// ---------------------------------------------------------------------------
__global__ void gemm_bf16_splitk(const float* __restrict__ A,
                                 const unsigned short* __restrict__ Bt,
                                 float* __restrict__ out){
  __shared__ unsigned short As[BM * 72];      // [64][64+8 pad] bf16
  __shared__ unsigned short Bs[N_EMB * 72];   // [128][64+8 pad] bf16

  const int tid   = threadIdx.x;
  const int bx    = blockIdx.x;
  const int mtile = bx & 63;
  const int s     = bx >> 6;
  const int m0    = mtile * BM;
  const int it0   = (s * IT_TOTAL) >> 4;
  const int it1   = ((s + 1) * IT_TOTAL) >> 4;

  const int lane = tid & 63;
  const int wv   = tid >> 6;      // wave 0..3
  const int col  = lane & 15;
  const int quad = lane >> 4;

  floatx4 acc[8];
#pragma unroll
  for (int c = 0; c < 8; ++c) acc[c] = (floatx4)0.0f;

  for (int it = it0; it < it1; ++it){
    const int kt = it * BK;
    __syncthreads();   // protect LDS from previous iter's frag reads

    // ---- stage A: 64 rows x 64 k fp32 -> bf16 in LDS ----
    if (kt + BK <= K_EFF){
#pragma unroll
      for (int p = 0; p < 2; ++p){
        const int row = p * 32 + (tid >> 3);
        const int c   = tid & 7;
        const floatx2* src =
            (const floatx2*)(A + (size_t)(m0 + row) * K_EFF + kt + c * 8);
        // rows alternate 8B/16B alignment (49998*4 mod 16 == 8) -> float2
        floatx2 f0 = __builtin_nontemporal_load(src + 0);
        floatx2 f1 = __builtin_nontemporal_load(src + 1);
        floatx2 f2 = __builtin_nontemporal_load(src + 2);
        floatx2 f3 = __builtin_nontemporal_load(src + 3);
        uintx4 pk;
        pk.x = f2bf(f0.x) | ((unsigned)f2bf(f0.y) << 16);
        pk.y = f2bf(f1.x) | ((unsigned)f2bf(f1.y) << 16);
        pk.z = f2bf(f2.x) | ((unsigned)f2bf(f2.y) << 16);
        pk.w = f2bf(f3.x) | ((unsigned)f2bf(f3.y) << 16);
        *(uintx4*)(&As[row * 72 + c * 8]) = pk;
      }
    } else {
      // ragged K tail (only it == 781): per-element guard, zero fill
#pragma unroll
      for (int p = 0; p < 2; ++p){
        const int row = p * 32 + (tid >> 3);
        const int c   = tid & 7;
        const float* src = A + (size_t)(m0 + row) * K_EFF;
        unsigned short v[8];
#pragma unroll
        for (int j = 0; j < 8; ++j){
          const int k = kt + c * 8 + j;
          v[j] = (k < K_EFF) ? f2bf(src[k]) : (unsigned short)0;
        }
        uintx4 pk;
        pk.x = v[0] | ((unsigned)v[1] << 16);
        pk.y = v[2] | ((unsigned)v[3] << 16);
        pk.z = v[4] | ((unsigned)v[5] << 16);
        pk.w = v[6] | ((unsigned)v[7] << 16);
        *(uintx4*)(&As[row * 72 + c * 8]) = pk;
      }
    }

    // ---- stage B: 128 n-rows x 64 k bf16 (already transposed+padded) ----
#pragma unroll
    for (int p = 0; p < 4; ++p){
      const int n = p * 32 + (tid >> 3);
      const int c = tid & 7;
      const uintx4 d = *(const uintx4*)(Bt + (size_t)n * K_PAD + kt + c * 8);
      *(uintx4*)(&Bs[n * 72 + c * 8]) = d;
    }
    __syncthreads();

    // ---- compute: 2 k-steps x 8 n-tiles of mfma 16x16x32 ----
#pragma unroll
    for (int ks = 0; ks < BK; ks += 32){
      const short8 af =
          *(const short8*)(&As[(16 * wv + col) * 72 + ks + quad * 8]);
#pragma unroll
      for (int c = 0; c < 8; ++c){
        const short8 bf =
            *(const short8*)(&Bs[(16 * c + col) * 72 + ks + quad * 8]);
        acc[c] = __builtin_amdgcn_mfma_f32_16x16x32_bf16(af, bf, acc[c], 0, 0, 0);
      }
    }
  }

  // ---- epilogue: C/D layout col=lane&15, row=quad*4+i; fp32 atomic add ----
  const int rbase = m0 + 16 * wv + quad * 4;
#pragma unroll
  for (int c = 0; c < 8; ++c){
#pragma unroll
    for (int i = 0; i < 4; ++i){
      atomicAdd(out + (size_t)(rbase + i) * N_EMB + 16 * c + col, acc[c][i]);
    }
  }
}

extern "C" void kernel_launch(void* const* d_in, const int* in_sizes, int n_in,
                              void* d_out, int out_size, void* d_ws, size_t ws_size,
                              hipStream_t stream) {
  const float* A = (const float*)d_in[0];   // input_ [4096][49998] fp32
  const float* W = (const float*)d_in[1];   // word2vecs [50000][128] fp32
  float* out = (float*)d_out;               // [4096][128] fp32
  unsigned short* Bt = (unsigned short*)d_ws;  // bf16 [128][K_PAD] = 12.8 MB

  // phase 0: zero out + build transposed bf16 table (stream-ordered)
  prep_bt<<<dim3(K_PAD / 64), dim3(256), 0, stream>>>(W, Bt, out);
  // phase 1: split-K GEMM, 64 M-tiles x 16 K-chunks = 1024 blocks
  gemm_bf16_splitk<<<dim3(64 * S_SPLIT), dim3(256), 0, stream>>>(A, Bt, out);
}